// Round 5
// baseline (11288.509 us; speedup 1.0000x reference)
//
#include <hip/hip_runtime.h>
#include <hip/hip_bf16.h>
#include <stdint.h>

typedef unsigned int u32;
typedef unsigned short u16;
typedef short bf16x8 __attribute__((ext_vector_type(8)));
typedef float f32x4 __attribute__((ext_vector_type(4)));
typedef u32 u32x4 __attribute__((ext_vector_type(4)));

#define T_STEPS 1024
#define BATCH   64
#define DIM     1024
#define NWG     64      // scan WGs (one per 16 hidden columns)
#define NHEAT   192     // heater WGs (clock-governor feed)
#define NTHR    512     // 8 waves
#define NMAT    3       // z, r, h
#define KSLICE  256     // K per wave (waves 0-3: x-part, 4-7: h-part)
#define DCOLS   16      // hidden columns per WG

// round-to-nearest-even f32 -> bf16 bits
__device__ __forceinline__ u16 f2bf(float f) {
  u32 u = __float_as_uint(f);
  return (u16)((u + 0x7FFFu + ((u >> 16) & 1u)) >> 16);
}
__device__ __forceinline__ float sigm(float x) { return 1.0f / (1.0f + __expf(-x)); }
__device__ __forceinline__ float tanh_f(float x) {
  x = fminf(8.0f, fmaxf(-8.0f, x));
  float e = __expf(2.0f * x);
  return (e - 1.0f) / (e + 1.0f);
}

// ---------------- init: zero flags + done word ----------------
__global__ void gru_init(u32* flags) {
  flags[threadIdx.x] = 0;
  flags[1024 + threadIdx.x] = 0;   // 8KB total: flag page + done page
}

// ---------------- one-time input f32 -> bf16 conversion ----------------
__global__ void gru_xconv(const float* __restrict__ in, u32* __restrict__ xb) {
  size_t i = (size_t)(blockIdx.x * 256 + threadIdx.x) * 8;
  f32x4 lo = *(const f32x4*)(in + i);
  f32x4 hi = *(const f32x4*)(in + i + 4);
  u32x4 o;
  o[0] = ((u32)f2bf(lo[1]) << 16) | f2bf(lo[0]);
  o[1] = ((u32)f2bf(lo[3]) << 16) | f2bf(lo[2]);
  o[2] = ((u32)f2bf(hi[1]) << 16) | f2bf(hi[0]);
  o[3] = ((u32)f2bf(hi[3]) << 16) | f2bf(hi[2]);
  *(u32x4*)(xb + i / 2) = o;
}

// ---------------- pack weights into per-wave register-fragment order ----------------
// k = (wv&3)*256 + ks*32 + (lane>>4)*8 + j   (contiguous-8 kappa; A-loads use the SAME kappa)
// col = wg*16 + (lane&15)
__global__ void gru_pack(const float* __restrict__ Wxz, const float* __restrict__ Whz,
                         const float* __restrict__ Wxr, const float* __restrict__ Whr,
                         const float* __restrict__ Wxh, const float* __restrict__ Whh,
                         u16* __restrict__ wpack) {
  int idx = blockIdx.x * 256 + threadIdx.x;
  if (idx >= NWG * 8 * NMAT * 8 * 64) return;
  int lane = idx & 63; int rest = idx >> 6;
  int ks = rest & 7;  rest >>= 3;
  int n  = rest % NMAT; rest /= NMAT;
  int wv = rest & 7;  int wg = rest >> 3;
  int d  = wg * DCOLS + (lane & 15);
  int k0 = (wv & 3) * KSLICE + ks * 32 + (lane >> 4) * 8;
  const float* W = (wv < 4) ? ((n == 0) ? Wxz : (n == 1) ? Wxr : Wxh)
                            : ((n == 0) ? Whz : (n == 1) ? Whr : Whh);
  u16* dst = wpack + (size_t)idx * 8;
#pragma unroll
  for (int j = 0; j < 8; ++j)
    dst[j] = f2bf(W[(size_t)(k0 + j) * DIM + d]);
}

// coherent 16B load with literal byte offset (device-coherent: bypass stale L1/L2)
#define LOADX4(dst, ptr, OFF) \
  asm volatile("global_load_dwordx4 %0, %1, off offset:" #OFF " sc0 sc1" \
               : "=v"(dst) : "v"(ptr))

#define HLOAD(B, pm) \
  LOADX4(B##0, (pm), 0);   LOADX4(B##1, (pm), 64);  LOADX4(B##2, (pm), 128); \
  LOADX4(B##3, (pm), 192); LOADX4(B##4, (pm), 256); LOADX4(B##5, (pm), 320); \
  LOADX4(B##6, (pm), 384); LOADX4(B##7, (pm), 448)

#define MF1(B, ks, m) { bf16x8 _a = __builtin_bit_cast(bf16x8, B); \
  acc[m][0] = __builtin_amdgcn_mfma_f32_16x16x32_bf16(_a, breg[0][ks], acc[m][0], 0, 0, 0); \
  acc[m][1] = __builtin_amdgcn_mfma_f32_16x16x32_bf16(_a, breg[1][ks], acc[m][1], 0, 0, 0); \
  acc[m][2] = __builtin_amdgcn_mfma_f32_16x16x32_bf16(_a, breg[2][ks], acc[m][2], 0, 0, 0); }

#define HMFMA(B, m) \
  MF1(B##0, 0, m); MF1(B##1, 1, m); MF1(B##2, 2, m); MF1(B##3, 3, m); \
  MF1(B##4, 4, m); MF1(B##5, 5, m); MF1(B##6, 6, m); MF1(B##7, 7, m)

#define WAITV(N) \
  asm volatile("s_waitcnt vmcnt(" #N ")" ::: "memory"); \
  __builtin_amdgcn_sched_barrier(0)

// ---------------- persistent scan kernel + heaters ----------------
// Blocks 0-63: GRU scan (producer-set barrier, register-resident weights).
// Blocks 64-255: heaters — dependent-FMA spin to hold the clock governor at high
// SCLK while the scan is latency-bound (throttle-test experiment). They poll a
// done flag every ~16K cycles (negligible fabric traffic) and exit when set.
template <bool XB>
__launch_bounds__(NTHR, 2)
__global__ void gru_scan(const float* __restrict__ inputs, const u32* __restrict__ xbf,
                         const float* __restrict__ bz, const float* __restrict__ br,
                         const float* __restrict__ bh,
                         const u16* __restrict__ wpack,
                         u16* hglob, u32* flags, float* __restrict__ out) {
  const int wg = blockIdx.x;
  if (wg >= NWG) {
    // ---------------- heater ----------------
    const u32* done = flags + 1024;
    float a = 1.0f + (float)(threadIdx.x & 63) * 1e-4f;
    for (;;) {
#pragma unroll 8
      for (int i = 0; i < 4096; ++i) a = __builtin_fmaf(a, 1.0000001f, 1e-9f);
      asm volatile("" : "+v"(a));          // keep the chain live
      u32 d = __hip_atomic_load(done, __ATOMIC_RELAXED, __HIP_MEMORY_SCOPE_AGENT);
      if (d) break;
    }
    return;
  }

  // partials: 24B cell/lane (4 data words + 2 pad) -> ds_write_b64 pairs and scalar
  // reads are both <=2-way bank aliased (free, m136). 144KB.
  __shared__ float part[8][4][NMAT][64][6];

  const int tid  = threadIdx.x;
  const int wv   = tid >> 6;
  const int lane = tid & 63;
  const int isH  = (wv >= 4);
  const int arow = lane & 15;
  const int akoff = (lane >> 4) * 8;

  // persistent B fragments: 24 x bf16x8; asm-laundered against remat/spill
  bf16x8 breg[NMAT][8];
  {
    const u16* wp = wpack + ((size_t)(wg * 8 + wv) * NMAT * 8 * 64) * 8;
#pragma unroll
    for (int n = 0; n < NMAT; ++n)
#pragma unroll
      for (int ks = 0; ks < 8; ++ks) {
        breg[n][ks] = *(const bf16x8*)(wp + ((n * 8 + ks) * 64 + lane) * 8);
        asm volatile("" : "+v"(breg[n][ks]));
      }
  }

  // elementwise ownership: thread -> (batch row, 2 adjacent d-columns)
  const int erow = tid >> 3;
  const int ep   = tid & 7;
  const int dbase = wg * DCOLS;
  const int d0 = dbase + 2 * ep;
  const float bz0 = bz[d0], bz1 = bz[d0 + 1];
  const float br0 = br[d0], br1 = br[d0 + 1];
  const float bh0 = bh[d0], bh1 = bh[d0 + 1];
  const int em = erow >> 4, er = erow & 15;
  const int cell0 = (er >> 2) * 16 + 2 * ep;   // partials cell for (row er, col 2ep)
  const int rr_rd = er & 3;                    // word within cell
  float hp0 = 0.f, hp1 = 0.f;                  // H_prev kept in f32 registers

  u32* hg32 = (u32*)hglob;
  // producer flag address for this h-wave (16 producers, lane&15 selects)
  const u32* fpoll = flags + (((wv - 4) & 3) * 16 + (lane & 15)) * 16;

#pragma unroll 1
  for (int t = 0; t < T_STEPS; ++t) {
    f32x4 acc[4][NMAT];
#pragma unroll
    for (int m = 0; m < 4; ++m)
#pragma unroll
      for (int n = 0; n < NMAT; ++n)
        acc[m][n] = (f32x4){0.f, 0.f, 0.f, 0.f};

    if (!isH) {
      // ---- x-part GEMM ----
      if (XB) {
        const u16* xp = (const u16*)xbf + (size_t)t * (BATCH * DIM) + wv * KSLICE + akoff;
#pragma unroll
        for (int m = 0; m < 4; ++m) {
          const u16* rp = xp + (size_t)(m * 16 + arow) * DIM;
#pragma unroll
          for (int ks = 0; ks < 8; ++ks) {
            bf16x8 av = *(const bf16x8*)(rp + ks * 32);
            MF1(__builtin_bit_cast(u32x4, av), ks, m);
          }
        }
      } else {
        const float* xp = inputs + (size_t)t * (BATCH * DIM) + wv * KSLICE + akoff;
#pragma unroll
        for (int m = 0; m < 4; ++m) {
          const float* rp = xp + (size_t)(m * 16 + arow) * DIM;
#pragma unroll
          for (int ks = 0; ks < 8; ++ks) {
            f32x4 lo = *(const f32x4*)(rp + ks * 32);
            f32x4 hi = *(const f32x4*)(rp + ks * 32 + 4);
            bf16x8 av;
            av[0] = (short)f2bf(lo[0]); av[1] = (short)f2bf(lo[1]);
            av[2] = (short)f2bf(lo[2]); av[3] = (short)f2bf(lo[3]);
            av[4] = (short)f2bf(hi[0]); av[5] = (short)f2bf(hi[1]);
            av[6] = (short)f2bf(hi[2]); av[7] = (short)f2bf(hi[3]);
            MF1(__builtin_bit_cast(u32x4, av), ks, m);
          }
        }
      }
    } else if (t > 0) {
      // ---- wait for THIS wave's 16 producer WGs to publish H(t-1) ----
      float spin = 1.0f + (float)lane * 1e-3f;
      for (;;) {
        u32 f = __hip_atomic_load(fpoll, __ATOMIC_RELAXED, __HIP_MEMORY_SCOPE_AGENT);
        if (__all((int)(f >= (u32)t))) break;
        // short dependent-FMA backoff (~100cy): pace fabric traffic, fast detect
#pragma unroll
        for (int s = 0; s < 24; ++s) spin = __builtin_fmaf(spin, 1.0000001f, 1e-9f);
        asm volatile("" : "+v"(spin));
      }
      asm volatile("" ::: "memory");
      // ---- h-part GEMM: pipelined coherent dwordx4 loads of H(t-1) ----
      const u32* hb = hg32 + (size_t)((t - 1) & 1) * (BATCH * DIM / 2)
                           + (size_t)arow * (DIM / 2) + (wv & 3) * 128 + (lane >> 4) * 4;
      u32x4 hA0, hA1, hA2, hA3, hA4, hA5, hA6, hA7;
      u32x4 hB0, hB1, hB2, hB3, hB4, hB5, hB6, hB7;
      HLOAD(hA, hb);               // m=0 rows
      HLOAD(hB, hb + 8192);        // m=1 rows (16 rows * 512 u32)
      WAITV(8);                    // m0 ready, m1 in flight
      HMFMA(hA, 0);
      HLOAD(hA, hb + 16384);       // m=2
      WAITV(8);                    // m1 ready
      HMFMA(hB, 1);
      HLOAD(hB, hb + 24576);       // m=3
      WAITV(8);                    // m2 ready
      HMFMA(hA, 2);
      WAITV(0);                    // m3 ready
      HMFMA(hB, 3);
    }
    // (t==0 h-waves: zero partials, H(-1)=0)

    // ---- publish partials to LDS: lane-cell layout, ds_write_b64 pairs ----
#pragma unroll
    for (int m = 0; m < 4; ++m)
#pragma unroll
      for (int n = 0; n < NMAT; ++n) {
        *(float2*)&part[wv][m][n][lane][0] = make_float2(acc[m][n][0], acc[m][n][1]);
        *(float2*)&part[wv][m][n][lane][2] = make_float2(acc[m][n][2], acc[m][n][3]);
      }
    __syncthreads();

    // ---- reduce + gates (all 512 threads; 2 outputs each) ----
    float zp = bz0, zq = bz1, rp = br0, rq = br1;
    float xh0 = bh0, xh1 = bh1, hh0 = 0.f, hh1 = 0.f;
#pragma unroll
    for (int w = 0; w < 8; ++w) {
      zp += part[w][em][0][cell0][rr_rd];
      zq += part[w][em][0][cell0 + 1][rr_rd];
      rp += part[w][em][1][cell0][rr_rd];
      rq += part[w][em][1][cell0 + 1][rr_rd];
      float h0 = part[w][em][2][cell0][rr_rd];
      float h1 = part[w][em][2][cell0 + 1][rr_rd];
      if (w < 4) { xh0 += h0; xh1 += h1; }   // x-part of candidate (NOT scaled by R)
      else       { hh0 += h0; hh1 += h1; }   // recurrent part (scaled by R)
    }
    float z0 = sigm(zp), z1 = sigm(zq);
    float r0 = sigm(rp), r1 = sigm(rq);
    float th0 = tanh_f(xh0 + r0 * hh0);
    float th1 = tanh_f(xh1 + r1 * hh1);
    float hn0 = z0 * hp0 + (1.f - z0) * th0;
    float hn1 = z1 * hp1 + (1.f - z1) * th1;
    hp0 = hn0; hp1 = hn1;

    // publish H(t) as bf16, device-coherent (double-buffered by step parity)
    {
      u32 pk = ((u32)f2bf(hn1) << 16) | (u32)f2bf(hn0);
      u32* hp = hg32 + (size_t)(t & 1) * (BATCH * DIM / 2)
                     + (size_t)erow * (DIM / 2) + (dbase >> 1) + ep;
      asm volatile("global_store_dword %0, %1, off sc0 sc1" :: "v"(hp), "v"(pk) : "memory");
    }
    // drain the H store (everything else is long since retired)
    asm volatile("s_waitcnt vmcnt(0)" ::: "memory");
    __syncthreads();
    if (tid == 0) {
      u32* fw = flags + wg * 16;
      u32 tv = (u32)(t + 1);
      asm volatile("global_store_dword %0, %1, off sc0 sc1" :: "v"(fw), "v"(tv) : "memory");
    }
    // out stores AFTER arrival: their drain overlaps the next step
    float* op = out + (size_t)t * (BATCH * DIM) + (size_t)erow * DIM + d0;
    *(float2*)op = make_float2(hn0, hn1);
    if (t == T_STEPS - 1) {
      float* fo = out + (size_t)T_STEPS * (BATCH * DIM) + (size_t)erow * DIM + d0;
      *(float2*)fo = make_float2(hn0, hn1);
    }
  }

  // release heaters
  if (wg == 0 && tid == 0) {
    u32* done = flags + 1024;
    u32 one = 1u;
    asm volatile("global_store_dword %0, %1, off sc0 sc1" :: "v"(done), "v"(one) : "memory");
  }
}

extern "C" void kernel_launch(void* const* d_in, const int* in_sizes, int n_in,
                              void* d_out, int out_size, void* d_ws, size_t ws_size,
                              hipStream_t stream) {
  const float* inputs = (const float*)d_in[0];
  const float* Wxz = (const float*)d_in[1];
  const float* Whz = (const float*)d_in[2];
  const float* bz  = (const float*)d_in[3];
  const float* Wxr = (const float*)d_in[4];
  const float* Whr = (const float*)d_in[5];
  const float* br  = (const float*)d_in[6];
  const float* Wxh = (const float*)d_in[7];
  const float* Whh = (const float*)d_in[8];
  const float* bh  = (const float*)d_in[9];
  float* out = (float*)d_out;

  // ws layout: [0,4K) flags | [4K,8K) done | [8K,+256K) H dbuf | wpack 12.6MB | xbf 128MB
  char* ws = (char*)d_ws;
  u32* flags = (u32*)ws;
  u16* hglob = (u16*)(ws + 8192);
  u16* wpack = (u16*)(ws + 8192 + 2 * BATCH * DIM * sizeof(u16));
  size_t base_need = 8192 + 2 * BATCH * DIM * 2 + (size_t)NWG * 8 * NMAT * 8 * 64 * 8 * 2;
  size_t xbf_off = (base_need + 4095) & ~(size_t)4095;
  u32* xbf = (u32*)(ws + xbf_off);
  size_t xbf_bytes = (size_t)T_STEPS * BATCH * DIM * 2;
  bool use_xb = (ws_size >= xbf_off + xbf_bytes);
  if (ws_size < base_need) return;  // insufficient workspace: fail visibly

  hipLaunchKernelGGL(gru_init, dim3(1), dim3(1024), 0, stream, flags);
  const int total = NWG * 8 * NMAT * 8 * 64;
  hipLaunchKernelGGL(gru_pack, dim3((total + 255) / 256), dim3(256), 0, stream,
                     Wxz, Whz, Wxr, Whr, Wxh, Whh, wpack);
  if (use_xb) {
    hipLaunchKernelGGL(gru_xconv, dim3(T_STEPS * BATCH * DIM / 8 / 256), dim3(256), 0, stream,
                       inputs, xbf);
    hipLaunchKernelGGL(gru_scan<true>, dim3(NWG + NHEAT), dim3(NTHR), 0, stream,
                       inputs, xbf, bz, br, bh, wpack, hglob, flags, out);
  } else {
    hipLaunchKernelGGL(gru_scan<false>, dim3(NWG + NHEAT), dim3(NTHR), 0, stream,
                       inputs, xbf, bz, br, bh, wpack, hglob, flags, out);
  }
}

// Round 6
// 10684.425 us; speedup vs baseline: 1.0565x; 1.0565x over previous
//
#include <hip/hip_runtime.h>
#include <hip/hip_bf16.h>
#include <stdint.h>

typedef unsigned int u32;
typedef unsigned short u16;
typedef short bf16x8 __attribute__((ext_vector_type(8)));
typedef float f32x4 __attribute__((ext_vector_type(4)));
typedef u32 u32x4 __attribute__((ext_vector_type(4)));

#define T_STEPS 1024
#define BATCH   64
#define DIM     1024
#define NWG     64      // one WG per 16 hidden columns
#define NTHR    512     // 8 waves
#define NMAT    3       // z, r, h
#define KSLICE  256     // K per wave (waves 0-3: x-part, 4-7: h-part)
#define DCOLS   16      // hidden columns per WG
#define HROW    512     // u32 per packed H row (1024 bf16 / 2)

// round-to-nearest-even f32 -> bf16 bits
__device__ __forceinline__ u16 f2bf(float f) {
  u32 u = __float_as_uint(f);
  return (u16)((u + 0x7FFFu + ((u >> 16) & 1u)) >> 16);
}
__device__ __forceinline__ float sigm(float x) { return 1.0f / (1.0f + __expf(-x)); }
__device__ __forceinline__ float tanh_f(float x) {
  x = fminf(8.0f, fmaxf(-8.0f, x));
  float e = __expf(2.0f * x);
  return (e - 1.0f) / (e + 1.0f);
}

// ---------------- init: zero flags ----------------
__global__ void gru_init(u32* flags) {
  flags[threadIdx.x] = 0;   // 4KB: 64 flags at 64B stride
}

// ---------------- one-time input f32 -> bf16 conversion ----------------
__global__ void gru_xconv(const float* __restrict__ in, u32* __restrict__ xb) {
  size_t i = (size_t)(blockIdx.x * 256 + threadIdx.x) * 8;
  f32x4 lo = *(const f32x4*)(in + i);
  f32x4 hi = *(const f32x4*)(in + i + 4);
  u32x4 o;
  o[0] = ((u32)f2bf(lo[1]) << 16) | f2bf(lo[0]);
  o[1] = ((u32)f2bf(lo[3]) << 16) | f2bf(lo[2]);
  o[2] = ((u32)f2bf(hi[1]) << 16) | f2bf(hi[0]);
  o[3] = ((u32)f2bf(hi[3]) << 16) | f2bf(hi[2]);
  *(u32x4*)(xb + i / 2) = o;
}

// ---------------- pack weights into per-wave register-fragment order ----------------
// k = (wv&3)*256 + ks*32 + (lane>>4)*8 + j   (contiguous-8 kappa; A-loads use the SAME kappa)
// col = wg*16 + (lane&15)
__global__ void gru_pack(const float* __restrict__ Wxz, const float* __restrict__ Whz,
                         const float* __restrict__ Wxr, const float* __restrict__ Whr,
                         const float* __restrict__ Wxh, const float* __restrict__ Whh,
                         u16* __restrict__ wpack) {
  int idx = blockIdx.x * 256 + threadIdx.x;
  if (idx >= NWG * 8 * NMAT * 8 * 64) return;
  int lane = idx & 63; int rest = idx >> 6;
  int ks = rest & 7;  rest >>= 3;
  int n  = rest % NMAT; rest /= NMAT;
  int wv = rest & 7;  int wg = rest >> 3;
  int d  = wg * DCOLS + (lane & 15);
  int k0 = (wv & 3) * KSLICE + ks * 32 + (lane >> 4) * 8;
  const float* W = (wv < 4) ? ((n == 0) ? Wxz : (n == 1) ? Wxr : Wxh)
                            : ((n == 0) ? Whz : (n == 1) ? Whr : Whh);
  u16* dst = wpack + (size_t)idx * 8;
#pragma unroll
  for (int j = 0; j < 8; ++j)
    dst[j] = f2bf(W[(size_t)(k0 + j) * DIM + d]);
}

// NORMAL (L2-cached) 16B load with literal byte offset — the no-reuse H-history
// address scheme makes cached loads safe: no L2 line for step t's slot can exist
// before flag(t) confirms the data reached the coherence point.
#define LOADX4N(dst, ptr, OFF) \
  asm volatile("global_load_dwordx4 %0, %1, off offset:" #OFF \
               : "=v"(dst) : "v"(ptr))

#define HLOAD(B, pm) \
  LOADX4N(B##0, (pm), 0);   LOADX4N(B##1, (pm), 64);  LOADX4N(B##2, (pm), 128); \
  LOADX4N(B##3, (pm), 192); LOADX4N(B##4, (pm), 256); LOADX4N(B##5, (pm), 320); \
  LOADX4N(B##6, (pm), 384); LOADX4N(B##7, (pm), 448)

#define MF1(B, ks, m) { bf16x8 _a = __builtin_bit_cast(bf16x8, B); \
  acc[m][0] = __builtin_amdgcn_mfma_f32_16x16x32_bf16(_a, breg[0][ks], acc[m][0], 0, 0, 0); \
  acc[m][1] = __builtin_amdgcn_mfma_f32_16x16x32_bf16(_a, breg[1][ks], acc[m][1], 0, 0, 0); \
  acc[m][2] = __builtin_amdgcn_mfma_f32_16x16x32_bf16(_a, breg[2][ks], acc[m][2], 0, 0, 0); }

#define HMFMA(B, m) \
  MF1(B##0, 0, m); MF1(B##1, 1, m); MF1(B##2, 2, m); MF1(B##3, 3, m); \
  MF1(B##4, 4, m); MF1(B##5, 5, m); MF1(B##6, 6, m); MF1(B##7, 7, m)

#define WAITV(N) \
  asm volatile("s_waitcnt vmcnt(" #N ")" ::: "memory"); \
  __builtin_amdgcn_sched_barrier(0)

// ---------------- persistent scan kernel ----------------
// H exchange via per-XCD L2: producers store H(t) coherently (sc0 sc1, write-through
// to IC) into a FRESH 256KB slot per step; consumers use NORMAL cached loads -> the
// 8 WGs of an XCD share one 128KB L2 fetch. Device-wide coherent traffic drops
// 8MB/step -> ~1MB/step. Producer-set flag barrier unchanged (r4 structure).
template <bool XB>
__launch_bounds__(NTHR, 2)
__global__ void gru_scan(const float* __restrict__ inputs, const u32* __restrict__ xbf,
                         const float* __restrict__ bz, const float* __restrict__ br,
                         const float* __restrict__ bh,
                         const u16* __restrict__ wpack,
                         u32* hhist, u32* flags, float* __restrict__ out) {
  // partials: 24B cell/lane (4 data words + 2 pad); <=2-way bank aliased (free). 144KB.
  __shared__ float part[8][4][NMAT][64][6];

  const int tid  = threadIdx.x;
  const int wg   = blockIdx.x;
  const int wv   = tid >> 6;
  const int lane = tid & 63;
  const int isH  = (wv >= 4);
  const int arow = lane & 15;
  const int akoff = (lane >> 4) * 8;

  // persistent B fragments: 24 x bf16x8; asm-laundered against remat/spill
  bf16x8 breg[NMAT][8];
  {
    const u16* wp = wpack + ((size_t)(wg * 8 + wv) * NMAT * 8 * 64) * 8;
#pragma unroll
    for (int n = 0; n < NMAT; ++n)
#pragma unroll
      for (int ks = 0; ks < 8; ++ks) {
        breg[n][ks] = *(const bf16x8*)(wp + ((n * 8 + ks) * 64 + lane) * 8);
        asm volatile("" : "+v"(breg[n][ks]));
      }
  }

  // elementwise ownership: thread -> (batch row, 2 adjacent d-columns)
  const int erow = tid >> 3;
  const int ep   = tid & 7;
  const int dbase = wg * DCOLS;
  const int d0 = dbase + 2 * ep;
  const float bz0 = bz[d0], bz1 = bz[d0 + 1];
  const float br0 = br[d0], br1 = br[d0 + 1];
  const float bh0 = bh[d0], bh1 = bh[d0 + 1];
  const int em = erow >> 4, er = erow & 15;
  const int cell0 = (er >> 2) * 16 + 2 * ep;   // partials cell for (row er, col 2ep)
  const int rr_rd = er & 3;                    // word within cell
  float hp0 = 0.f, hp1 = 0.f;                  // H_prev kept in f32 registers

  // producer flag address for this h-wave (16 producers, lane&15 selects)
  const u32* fpoll = flags + (((wv - 4) & 3) * 16 + (lane & 15)) * 16;

#pragma unroll 1
  for (int t = 0; t < T_STEPS; ++t) {
    f32x4 acc[4][NMAT];
#pragma unroll
    for (int m = 0; m < 4; ++m)
#pragma unroll
      for (int n = 0; n < NMAT; ++n)
        acc[m][n] = (f32x4){0.f, 0.f, 0.f, 0.f};

    if (!isH) {
      // ---- warm-touch inputs[t+1] slice into this XCD's L2 (fire-and-ack;
      //      x-waves have slack; pulls the per-step HBM cold miss off the chain) ----
      u32 tch = 0;
      if (t + 1 < T_STEPS) {
        constexpr int LPR = XB ? 8 : 16;       // 64B lines per row-slice
        const char* nb = XB
          ? (const char*)((const u16*)xbf + (size_t)(t + 1) * (BATCH * DIM) + wv * KSLICE)
          : (const char*)(inputs + (size_t)(t + 1) * (BATCH * DIM) + wv * KSLICE);
        constexpr int ROWB = XB ? (DIM * 2) : (DIM * 4);
#pragma unroll
        for (int i = 0; i < LPR; ++i) {
          int L = i * 64 + lane;
          const u32* tp = (const u32*)(nb + (size_t)(L / LPR) * ROWB + (L % LPR) * 64);
          tch ^= *tp;
        }
      }
      // ---- x-part GEMM ----
      if (XB) {
        const u16* xp = (const u16*)xbf + (size_t)t * (BATCH * DIM) + wv * KSLICE + akoff;
#pragma unroll
        for (int m = 0; m < 4; ++m) {
          const u16* rp = xp + (size_t)(m * 16 + arow) * DIM;
#pragma unroll
          for (int ks = 0; ks < 8; ++ks) {
            bf16x8 av = *(const bf16x8*)(rp + ks * 32);
            MF1(__builtin_bit_cast(u32x4, av), ks, m);
          }
        }
      } else {
        const float* xp = inputs + (size_t)t * (BATCH * DIM) + wv * KSLICE + akoff;
#pragma unroll
        for (int m = 0; m < 4; ++m) {
          const float* rp = xp + (size_t)(m * 16 + arow) * DIM;
#pragma unroll
          for (int ks = 0; ks < 8; ++ks) {
            f32x4 lo = *(const f32x4*)(rp + ks * 32);
            f32x4 hi = *(const f32x4*)(rp + ks * 32 + 4);
            bf16x8 av;
            av[0] = (short)f2bf(lo[0]); av[1] = (short)f2bf(lo[1]);
            av[2] = (short)f2bf(lo[2]); av[3] = (short)f2bf(lo[3]);
            av[4] = (short)f2bf(hi[0]); av[5] = (short)f2bf(hi[1]);
            av[6] = (short)f2bf(hi[2]); av[7] = (short)f2bf(hi[3]);
            MF1(__builtin_bit_cast(u32x4, av), ks, m);
          }
        }
      }
      asm volatile("" :: "v"(tch));   // keep touches live (rule #17); stall lands here
    } else if (t > 0) {
      // ---- wait for THIS wave's 16 producer WGs to publish H(t-1) ----
      float spin = 1.0f + (float)lane * 1e-3f;
      for (;;) {
        u32 f = __hip_atomic_load(fpoll, __ATOMIC_RELAXED, __HIP_MEMORY_SCOPE_AGENT);
        if (__all((int)(f >= (u32)t))) break;
#pragma unroll
        for (int s = 0; s < 24; ++s) spin = __builtin_fmaf(spin, 1.0000001f, 1e-9f);
        asm volatile("" : "+v"(spin));
      }
      asm volatile("" ::: "memory");
      // ---- h-part GEMM: NORMAL cached loads from the fresh H(t-1) slot ----
      const u32* hb = hhist + (size_t)(t - 1) * (BATCH * HROW)
                            + (size_t)arow * HROW + (wv & 3) * 128 + (lane >> 4) * 4;
      u32x4 hA0, hA1, hA2, hA3, hA4, hA5, hA6, hA7;
      u32x4 hB0, hB1, hB2, hB3, hB4, hB5, hB6, hB7;
      HLOAD(hA, hb);               // m=0 rows
      HLOAD(hB, hb + 8192);        // m=1 rows (16 rows * 512 u32)
      WAITV(8);                    // m0 ready, m1 in flight
      HMFMA(hA, 0);
      HLOAD(hA, hb + 16384);       // m=2
      WAITV(8);                    // m1 ready
      HMFMA(hB, 1);
      HLOAD(hB, hb + 24576);       // m=3
      WAITV(8);                    // m2 ready
      HMFMA(hA, 2);
      WAITV(0);                    // m3 ready
      HMFMA(hB, 3);
    }
    // (t==0 h-waves: zero partials, H(-1)=0)

    // ---- publish partials to LDS: lane-cell layout, ds_write_b64 pairs ----
#pragma unroll
    for (int m = 0; m < 4; ++m)
#pragma unroll
      for (int n = 0; n < NMAT; ++n) {
        *(float2*)&part[wv][m][n][lane][0] = make_float2(acc[m][n][0], acc[m][n][1]);
        *(float2*)&part[wv][m][n][lane][2] = make_float2(acc[m][n][2], acc[m][n][3]);
      }
    __syncthreads();

    // ---- reduce + gates (all 512 threads; 2 outputs each) ----
    float zp = bz0, zq = bz1, rp = br0, rq = br1;
    float xh0 = bh0, xh1 = bh1, hh0 = 0.f, hh1 = 0.f;
#pragma unroll
    for (int w = 0; w < 8; ++w) {
      zp += part[w][em][0][cell0][rr_rd];
      zq += part[w][em][0][cell0 + 1][rr_rd];
      rp += part[w][em][1][cell0][rr_rd];
      rq += part[w][em][1][cell0 + 1][rr_rd];
      float h0 = part[w][em][2][cell0][rr_rd];
      float h1 = part[w][em][2][cell0 + 1][rr_rd];
      if (w < 4) { xh0 += h0; xh1 += h1; }   // x-part of candidate (NOT scaled by R)
      else       { hh0 += h0; hh1 += h1; }   // recurrent part (scaled by R)
    }
    float z0 = sigm(zp), z1 = sigm(zq);
    float r0 = sigm(rp), r1 = sigm(rq);
    float th0 = tanh_f(xh0 + r0 * hh0);
    float th1 = tanh_f(xh1 + r1 * hh1);
    float hn0 = z0 * hp0 + (1.f - z0) * th0;
    float hn1 = z1 * hp1 + (1.f - z1) * th1;
    hp0 = hn0; hp1 = hn1;

    // publish H(t) to the FRESH slot t, device-coherent write-through
    {
      u32 pk = ((u32)f2bf(hn1) << 16) | (u32)f2bf(hn0);
      u32* hp = hhist + (size_t)t * (BATCH * HROW)
                      + (size_t)erow * HROW + (dbase >> 1) + ep;
      asm volatile("global_store_dword %0, %1, off sc0 sc1" :: "v"(hp), "v"(pk) : "memory");
    }
    // drain the H store, then arrival flag
    asm volatile("s_waitcnt vmcnt(0)" ::: "memory");
    __syncthreads();
    if (tid == 0) {
      u32* fw = flags + wg * 16;
      u32 tv = (u32)(t + 1);
      asm volatile("global_store_dword %0, %1, off sc0 sc1" :: "v"(fw), "v"(tv) : "memory");
    }
    // out stores AFTER arrival: their drain overlaps the next step
    float* op = out + (size_t)t * (BATCH * DIM) + (size_t)erow * DIM + d0;
    *(float2*)op = make_float2(hn0, hn1);
    if (t == T_STEPS - 1) {
      float* fo = out + (size_t)T_STEPS * (BATCH * DIM) + (size_t)erow * DIM + d0;
      *(float2*)fo = make_float2(hn0, hn1);
    }
  }
}

extern "C" void kernel_launch(void* const* d_in, const int* in_sizes, int n_in,
                              void* d_out, int out_size, void* d_ws, size_t ws_size,
                              hipStream_t stream) {
  const float* inputs = (const float*)d_in[0];
  const float* Wxz = (const float*)d_in[1];
  const float* Whz = (const float*)d_in[2];
  const float* bz  = (const float*)d_in[3];
  const float* Wxr = (const float*)d_in[4];
  const float* Whr = (const float*)d_in[5];
  const float* br  = (const float*)d_in[6];
  const float* Wxh = (const float*)d_in[7];
  const float* Whh = (const float*)d_in[8];
  const float* bh  = (const float*)d_in[9];
  float* out = (float*)d_out;

  // ws layout: [0,4K) flags | [4K,8K) spare | [8K, +128MB) H history (no-reuse slots)
  //            | wpack 12.6MB | xbf 128MB (optional)
  char* ws = (char*)d_ws;
  u32* flags = (u32*)ws;
  u32* hhist = (u32*)(ws + 8192);
  size_t hhist_bytes = (size_t)T_STEPS * BATCH * HROW * 4;   // 128MB
  u16* wpack = (u16*)(ws + 8192 + hhist_bytes);
  size_t wpack_bytes = (size_t)NWG * 8 * NMAT * 8 * 64 * 8 * 2;
  size_t base_need = 8192 + hhist_bytes + wpack_bytes;       // ~140MB (fits verified ws)
  size_t xbf_off = (base_need + 4095) & ~(size_t)4095;
  u32* xbf = (u32*)(ws + xbf_off);
  size_t xbf_bytes = (size_t)T_STEPS * BATCH * DIM * 2;
  bool use_xb = (ws_size >= xbf_off + xbf_bytes);
  if (ws_size < base_need) return;  // insufficient workspace: fail visibly

  hipLaunchKernelGGL(gru_init, dim3(1), dim3(1024), 0, stream, flags);
  const int total = NWG * 8 * NMAT * 8 * 64;
  hipLaunchKernelGGL(gru_pack, dim3((total + 255) / 256), dim3(256), 0, stream,
                     Wxz, Whz, Wxr, Whr, Wxh, Whh, wpack);
  if (use_xb) {
    hipLaunchKernelGGL(gru_xconv, dim3(T_STEPS * BATCH * DIM / 8 / 256), dim3(256), 0, stream,
                       inputs, xbf);
    hipLaunchKernelGGL(gru_scan<true>, dim3(NWG), dim3(NTHR), 0, stream,
                       inputs, xbf, bz, br, bh, wpack, hhist, flags, out);
  } else {
    hipLaunchKernelGGL(gru_scan<false>, dim3(NWG), dim3(NTHR), 0, stream,
                       inputs, xbf, bz, br, bh, wpack, hhist, flags, out);
  }
}

// Round 7
// 10657.956 us; speedup vs baseline: 1.0592x; 1.0025x over previous
//
#include <hip/hip_runtime.h>
#include <hip/hip_bf16.h>
#include <stdint.h>

typedef unsigned int u32;
typedef unsigned short u16;
typedef short bf16x8 __attribute__((ext_vector_type(8)));
typedef float f32x4 __attribute__((ext_vector_type(4)));
typedef u32 u32x4 __attribute__((ext_vector_type(4)));

#define T_STEPS 1024
#define BATCH   64
#define DIM     1024
#define NWG     64      // scan WGs (one per 16 hidden columns)
#define NHEAT   16      // memory-streaming heater WGs (FCLK/MCLK governor feed)
#define NTHR    512     // 8 waves
#define NMAT    3       // z, r, h
#define KSLICE  256     // K per wave (waves 0-3: x-part, 4-7: h-part)
#define DCOLS   16      // hidden columns per WG
#define HROW    512     // u32 per packed H row (1024 bf16 / 2)

// round-to-nearest-even f32 -> bf16 bits
__device__ __forceinline__ u16 f2bf(float f) {
  u32 u = __float_as_uint(f);
  return (u16)((u + 0x7FFFu + ((u >> 16) & 1u)) >> 16);
}
__device__ __forceinline__ float sigm(float x) { return 1.0f / (1.0f + __expf(-x)); }
__device__ __forceinline__ float tanh_f(float x) {
  x = fminf(8.0f, fmaxf(-8.0f, x));
  float e = __expf(2.0f * x);
  return (e - 1.0f) / (e + 1.0f);
}

// ---------------- init: zero flags + done page ----------------
__global__ void gru_init(u32* flags) {
  flags[threadIdx.x] = 0;             // flag page (4KB)
  flags[1024 + threadIdx.x] = 0;      // done page (4KB)
}

// ---------------- one-time input f32 -> bf16 conversion ----------------
__global__ void gru_xconv(const float* __restrict__ in, u32* __restrict__ xb) {
  size_t i = (size_t)(blockIdx.x * 256 + threadIdx.x) * 8;
  f32x4 lo = *(const f32x4*)(in + i);
  f32x4 hi = *(const f32x4*)(in + i + 4);
  u32x4 o;
  o[0] = ((u32)f2bf(lo[1]) << 16) | f2bf(lo[0]);
  o[1] = ((u32)f2bf(lo[3]) << 16) | f2bf(lo[2]);
  o[2] = ((u32)f2bf(hi[1]) << 16) | f2bf(hi[0]);
  o[3] = ((u32)f2bf(hi[3]) << 16) | f2bf(hi[2]);
  *(u32x4*)(xb + i / 2) = o;
}

// ---------------- pack weights into per-wave register-fragment order ----------------
// k = (wv&3)*256 + ks*32 + (lane>>4)*8 + j   (contiguous-8 kappa; A-loads use the SAME kappa)
// col = wg*16 + (lane&15)
__global__ void gru_pack(const float* __restrict__ Wxz, const float* __restrict__ Whz,
                         const float* __restrict__ Wxr, const float* __restrict__ Whr,
                         const float* __restrict__ Wxh, const float* __restrict__ Whh,
                         u16* __restrict__ wpack) {
  int idx = blockIdx.x * 256 + threadIdx.x;
  if (idx >= NWG * 8 * NMAT * 8 * 64) return;
  int lane = idx & 63; int rest = idx >> 6;
  int ks = rest & 7;  rest >>= 3;
  int n  = rest % NMAT; rest /= NMAT;
  int wv = rest & 7;  int wg = rest >> 3;
  int d  = wg * DCOLS + (lane & 15);
  int k0 = (wv & 3) * KSLICE + ks * 32 + (lane >> 4) * 8;
  const float* W = (wv < 4) ? ((n == 0) ? Wxz : (n == 1) ? Wxr : Wxh)
                            : ((n == 0) ? Whz : (n == 1) ? Whr : Whh);
  u16* dst = wpack + (size_t)idx * 8;
#pragma unroll
  for (int j = 0; j < 8; ++j)
    dst[j] = f2bf(W[(size_t)(k0 + j) * DIM + d]);
}

// NORMAL (L2-cached) 16B load with literal byte offset — safe via no-reuse H history
#define LOADX4N(dst, ptr, OFF) \
  asm volatile("global_load_dwordx4 %0, %1, off offset:" #OFF \
               : "=v"(dst) : "v"(ptr))

// non-temporal streaming load (heaters): generate HBM/fabric traffic w/o cache pollution
#define LOADX4NT(dst, ptr, OFF) \
  asm volatile("global_load_dwordx4 %0, %1, off offset:" #OFF " nt" \
               : "=v"(dst) : "v"(ptr))

#define HLOAD(B, pm) \
  LOADX4N(B##0, (pm), 0);   LOADX4N(B##1, (pm), 64);  LOADX4N(B##2, (pm), 128); \
  LOADX4N(B##3, (pm), 192); LOADX4N(B##4, (pm), 256); LOADX4N(B##5, (pm), 320); \
  LOADX4N(B##6, (pm), 384); LOADX4N(B##7, (pm), 448)

#define MF1(B, ks, m) { bf16x8 _a = __builtin_bit_cast(bf16x8, B); \
  acc[m][0] = __builtin_amdgcn_mfma_f32_16x16x32_bf16(_a, breg[0][ks], acc[m][0], 0, 0, 0); \
  acc[m][1] = __builtin_amdgcn_mfma_f32_16x16x32_bf16(_a, breg[1][ks], acc[m][1], 0, 0, 0); \
  acc[m][2] = __builtin_amdgcn_mfma_f32_16x16x32_bf16(_a, breg[2][ks], acc[m][2], 0, 0, 0); }

#define HMFMA(B, m) \
  MF1(B##0, 0, m); MF1(B##1, 1, m); MF1(B##2, 2, m); MF1(B##3, 3, m); \
  MF1(B##4, 4, m); MF1(B##5, 5, m); MF1(B##6, 6, m); MF1(B##7, 7, m)

#define WAITV(N) \
  asm volatile("s_waitcnt vmcnt(" #N ")" ::: "memory"); \
  __builtin_amdgcn_sched_barrier(0)

// ---------------- persistent scan kernel + memory heaters ----------------
// Blocks 0-63: GRU scan, identical to round 6 (H via per-XCD L2, producer-set flags).
// Blocks 64-79: MEMORY heaters — stream nt loads over the 256MB inputs buffer to hold
// the FCLK/MCLK governor at high clocks (r5's VALU heaters fed only the compute-clock
// domain; this is the memory-domain test). Exit on done flag.
template <bool XB>
__launch_bounds__(NTHR, 2)
__global__ void gru_scan(const float* __restrict__ inputs, const u32* __restrict__ xbf,
                         const float* __restrict__ bz, const float* __restrict__ br,
                         const float* __restrict__ bh,
                         const u16* __restrict__ wpack,
                         u32* hhist, u32* flags, float* __restrict__ out) {
  const int wg = blockIdx.x;
  if (wg >= NWG) {
    // ---------------- memory-streaming heater ----------------
    const u32* done = flags + 1024;
    const int hw   = (wg - NWG) * 8 + (threadIdx.x >> 6);   // heater wave id, 0..127
    const int lane = threadIdx.x & 63;
    // each wave owns a disjoint 2MB chunk of inputs (256MB total)
    const char* base = (const char*)inputs + (size_t)hw * (2u << 20) + (size_t)lane * 16;
    u32x4 s0, s1, s2, s3, s4, s5, s6, s7;
    u32 sink = 0;
    for (;;) {
      for (int off = 0; off < (2 << 20); off += 64 * 16 * 8) {
        const char* p = base + off;
        LOADX4NT(s0, p, 0);     LOADX4NT(s1, p, 1024);  LOADX4NT(s2, p, 2048);
        LOADX4NT(s3, p, 3072);  LOADX4NT(s4, p, 0);     // reuse offsets are fine (traffic only)
        LOADX4NT(s5, p, 1024);  LOADX4NT(s6, p, 2048);  LOADX4NT(s7, p, 3072);
        asm volatile("s_waitcnt vmcnt(0)" ::: "memory");
        sink ^= s0[0] ^ s1[0] ^ s2[0] ^ s3[0] ^ s4[0] ^ s5[0] ^ s6[0] ^ s7[0];
        u32 d = __hip_atomic_load(done, __ATOMIC_RELAXED, __HIP_MEMORY_SCOPE_AGENT);
        if (d) { asm volatile("" :: "v"(sink)); return; }
      }
    }
  }

  // partials: 24B cell/lane (4 data words + 2 pad); <=2-way bank aliased (free). 144KB.
  __shared__ float part[8][4][NMAT][64][6];

  const int tid  = threadIdx.x;
  const int wv   = tid >> 6;
  const int lane = tid & 63;
  const int isH  = (wv >= 4);
  const int arow = lane & 15;
  const int akoff = (lane >> 4) * 8;

  // persistent B fragments: 24 x bf16x8; asm-laundered against remat/spill
  bf16x8 breg[NMAT][8];
  {
    const u16* wp = wpack + ((size_t)(wg * 8 + wv) * NMAT * 8 * 64) * 8;
#pragma unroll
    for (int n = 0; n < NMAT; ++n)
#pragma unroll
      for (int ks = 0; ks < 8; ++ks) {
        breg[n][ks] = *(const bf16x8*)(wp + ((n * 8 + ks) * 64 + lane) * 8);
        asm volatile("" : "+v"(breg[n][ks]));
      }
  }

  // elementwise ownership: thread -> (batch row, 2 adjacent d-columns)
  const int erow = tid >> 3;
  const int ep   = tid & 7;
  const int dbase = wg * DCOLS;
  const int d0 = dbase + 2 * ep;
  const float bz0 = bz[d0], bz1 = bz[d0 + 1];
  const float br0 = br[d0], br1 = br[d0 + 1];
  const float bh0 = bh[d0], bh1 = bh[d0 + 1];
  const int em = erow >> 4, er = erow & 15;
  const int cell0 = (er >> 2) * 16 + 2 * ep;   // partials cell for (row er, col 2ep)
  const int rr_rd = er & 3;                    // word within cell
  float hp0 = 0.f, hp1 = 0.f;                  // H_prev kept in f32 registers

  // producer flag address for this h-wave (16 producers, lane&15 selects)
  const u32* fpoll = flags + (((wv - 4) & 3) * 16 + (lane & 15)) * 16;

#pragma unroll 1
  for (int t = 0; t < T_STEPS; ++t) {
    f32x4 acc[4][NMAT];
#pragma unroll
    for (int m = 0; m < 4; ++m)
#pragma unroll
      for (int n = 0; n < NMAT; ++n)
        acc[m][n] = (f32x4){0.f, 0.f, 0.f, 0.f};

    if (!isH) {
      // ---- warm-touch inputs[t+1] slice into this XCD's L2 ----
      u32 tch = 0;
      if (t + 1 < T_STEPS) {
        constexpr int LPR = XB ? 8 : 16;       // 64B lines per row-slice
        const char* nb = XB
          ? (const char*)((const u16*)xbf + (size_t)(t + 1) * (BATCH * DIM) + wv * KSLICE)
          : (const char*)(inputs + (size_t)(t + 1) * (BATCH * DIM) + wv * KSLICE);
        constexpr int ROWB = XB ? (DIM * 2) : (DIM * 4);
#pragma unroll
        for (int i = 0; i < LPR; ++i) {
          int L = i * 64 + lane;
          const u32* tp = (const u32*)(nb + (size_t)(L / LPR) * ROWB + (L % LPR) * 64);
          tch ^= *tp;
        }
      }
      // ---- x-part GEMM ----
      if (XB) {
        const u16* xp = (const u16*)xbf + (size_t)t * (BATCH * DIM) + wv * KSLICE + akoff;
#pragma unroll
        for (int m = 0; m < 4; ++m) {
          const u16* rp = xp + (size_t)(m * 16 + arow) * DIM;
#pragma unroll
          for (int ks = 0; ks < 8; ++ks) {
            bf16x8 av = *(const bf16x8*)(rp + ks * 32);
            MF1(__builtin_bit_cast(u32x4, av), ks, m);
          }
        }
      } else {
        const float* xp = inputs + (size_t)t * (BATCH * DIM) + wv * KSLICE + akoff;
#pragma unroll
        for (int m = 0; m < 4; ++m) {
          const float* rp = xp + (size_t)(m * 16 + arow) * DIM;
#pragma unroll
          for (int ks = 0; ks < 8; ++ks) {
            f32x4 lo = *(const f32x4*)(rp + ks * 32);
            f32x4 hi = *(const f32x4*)(rp + ks * 32 + 4);
            bf16x8 av;
            av[0] = (short)f2bf(lo[0]); av[1] = (short)f2bf(lo[1]);
            av[2] = (short)f2bf(lo[2]); av[3] = (short)f2bf(lo[3]);
            av[4] = (short)f2bf(hi[0]); av[5] = (short)f2bf(hi[1]);
            av[6] = (short)f2bf(hi[2]); av[7] = (short)f2bf(hi[3]);
            MF1(__builtin_bit_cast(u32x4, av), ks, m);
          }
        }
      }
      asm volatile("" :: "v"(tch));   // keep touches live (rule #17)
    } else if (t > 0) {
      // ---- wait for THIS wave's 16 producer WGs to publish H(t-1) ----
      float spin = 1.0f + (float)lane * 1e-3f;
      for (;;) {
        u32 f = __hip_atomic_load(fpoll, __ATOMIC_RELAXED, __HIP_MEMORY_SCOPE_AGENT);
        if (__all((int)(f >= (u32)t))) break;
#pragma unroll
        for (int s = 0; s < 24; ++s) spin = __builtin_fmaf(spin, 1.0000001f, 1e-9f);
        asm volatile("" : "+v"(spin));
      }
      asm volatile("" ::: "memory");
      // ---- h-part GEMM: NORMAL cached loads from the fresh H(t-1) slot ----
      const u32* hb = hhist + (size_t)(t - 1) * (BATCH * HROW)
                            + (size_t)arow * HROW + (wv & 3) * 128 + (lane >> 4) * 4;
      u32x4 hA0, hA1, hA2, hA3, hA4, hA5, hA6, hA7;
      u32x4 hB0, hB1, hB2, hB3, hB4, hB5, hB6, hB7;
      HLOAD(hA, hb);               // m=0 rows
      HLOAD(hB, hb + 8192);        // m=1 rows (16 rows * 512 u32)
      WAITV(8);                    // m0 ready, m1 in flight
      HMFMA(hA, 0);
      HLOAD(hA, hb + 16384);       // m=2
      WAITV(8);                    // m1 ready
      HMFMA(hB, 1);
      HLOAD(hB, hb + 24576);       // m=3
      WAITV(8);                    // m2 ready
      HMFMA(hA, 2);
      WAITV(0);                    // m3 ready
      HMFMA(hB, 3);
    }
    // (t==0 h-waves: zero partials, H(-1)=0)

    // ---- publish partials to LDS: lane-cell layout, ds_write_b64 pairs ----
#pragma unroll
    for (int m = 0; m < 4; ++m)
#pragma unroll
      for (int n = 0; n < NMAT; ++n) {
        *(float2*)&part[wv][m][n][lane][0] = make_float2(acc[m][n][0], acc[m][n][1]);
        *(float2*)&part[wv][m][n][lane][2] = make_float2(acc[m][n][2], acc[m][n][3]);
      }
    __syncthreads();

    // ---- reduce + gates (all 512 threads; 2 outputs each) ----
    float zp = bz0, zq = bz1, rp = br0, rq = br1;
    float xh0 = bh0, xh1 = bh1, hh0 = 0.f, hh1 = 0.f;
#pragma unroll
    for (int w = 0; w < 8; ++w) {
      zp += part[w][em][0][cell0][rr_rd];
      zq += part[w][em][0][cell0 + 1][rr_rd];
      rp += part[w][em][1][cell0][rr_rd];
      rq += part[w][em][1][cell0 + 1][rr_rd];
      float h0 = part[w][em][2][cell0][rr_rd];
      float h1 = part[w][em][2][cell0 + 1][rr_rd];
      if (w < 4) { xh0 += h0; xh1 += h1; }   // x-part of candidate (NOT scaled by R)
      else       { hh0 += h0; hh1 += h1; }   // recurrent part (scaled by R)
    }
    float z0 = sigm(zp), z1 = sigm(zq);
    float r0 = sigm(rp), r1 = sigm(rq);
    float th0 = tanh_f(xh0 + r0 * hh0);
    float th1 = tanh_f(xh1 + r1 * hh1);
    float hn0 = z0 * hp0 + (1.f - z0) * th0;
    float hn1 = z1 * hp1 + (1.f - z1) * th1;
    hp0 = hn0; hp1 = hn1;

    // publish H(t) to the FRESH slot t, device-coherent write-through
    {
      u32 pk = ((u32)f2bf(hn1) << 16) | (u32)f2bf(hn0);
      u32* hp = hhist + (size_t)t * (BATCH * HROW)
                      + (size_t)erow * HROW + (dbase >> 1) + ep;
      asm volatile("global_store_dword %0, %1, off sc0 sc1" :: "v"(hp), "v"(pk) : "memory");
    }
    // drain the H store, then arrival flag
    asm volatile("s_waitcnt vmcnt(0)" ::: "memory");
    __syncthreads();
    if (tid == 0) {
      u32* fw = flags + wg * 16;
      u32 tv = (u32)(t + 1);
      asm volatile("global_store_dword %0, %1, off sc0 sc1" :: "v"(fw), "v"(tv) : "memory");
    }
    // out stores AFTER arrival: their drain overlaps the next step
    float* op = out + (size_t)t * (BATCH * DIM) + (size_t)erow * DIM + d0;
    *(float2*)op = make_float2(hn0, hn1);
    if (t == T_STEPS - 1) {
      float* fo = out + (size_t)T_STEPS * (BATCH * DIM) + (size_t)erow * DIM + d0;
      *(float2*)fo = make_float2(hn0, hn1);
    }
  }

  // release heaters
  if (wg == 0 && tid == 0) {
    u32* done = flags + 1024;
    u32 one = 1u;
    asm volatile("global_store_dword %0, %1, off sc0 sc1" :: "v"(done), "v"(one) : "memory");
  }
}

extern "C" void kernel_launch(void* const* d_in, const int* in_sizes, int n_in,
                              void* d_out, int out_size, void* d_ws, size_t ws_size,
                              hipStream_t stream) {
  const float* inputs = (const float*)d_in[0];
  const float* Wxz = (const float*)d_in[1];
  const float* Whz = (const float*)d_in[2];
  const float* bz  = (const float*)d_in[3];
  const float* Wxr = (const float*)d_in[4];
  const float* Whr = (const float*)d_in[5];
  const float* br  = (const float*)d_in[6];
  const float* Wxh = (const float*)d_in[7];
  const float* Whh = (const float*)d_in[8];
  const float* bh  = (const float*)d_in[9];
  float* out = (float*)d_out;

  // ws layout: [0,4K) flags | [4K,8K) done | [8K, +128MB) H history (no-reuse slots)
  //            | wpack 12.6MB | xbf 128MB (optional)
  char* ws = (char*)d_ws;
  u32* flags = (u32*)ws;
  u32* hhist = (u32*)(ws + 8192);
  size_t hhist_bytes = (size_t)T_STEPS * BATCH * HROW * 4;   // 128MB
  u16* wpack = (u16*)(ws + 8192 + hhist_bytes);
  size_t wpack_bytes = (size_t)NWG * 8 * NMAT * 8 * 64 * 8 * 2;
  size_t base_need = 8192 + hhist_bytes + wpack_bytes;
  size_t xbf_off = (base_need + 4095) & ~(size_t)4095;
  u32* xbf = (u32*)(ws + xbf_off);
  size_t xbf_bytes = (size_t)T_STEPS * BATCH * DIM * 2;
  bool use_xb = (ws_size >= xbf_off + xbf_bytes);
  if (ws_size < base_need) return;  // insufficient workspace: fail visibly

  hipLaunchKernelGGL(gru_init, dim3(1), dim3(1024), 0, stream, flags);
  const int total = NWG * 8 * NMAT * 8 * 64;
  hipLaunchKernelGGL(gru_pack, dim3((total + 255) / 256), dim3(256), 0, stream,
                     Wxz, Whz, Wxr, Whr, Wxh, Whh, wpack);
  if (use_xb) {
    hipLaunchKernelGGL(gru_xconv, dim3(T_STEPS * BATCH * DIM / 8 / 256), dim3(256), 0, stream,
                       inputs, xbf);
    hipLaunchKernelGGL(gru_scan<true>, dim3(NWG + NHEAT), dim3(NTHR), 0, stream,
                       inputs, xbf, bz, br, bh, wpack, hhist, flags, out);
  } else {
    hipLaunchKernelGGL(gru_scan<false>, dim3(NWG + NHEAT), dim3(NTHR), 0, stream,
                       inputs, xbf, bz, br, bh, wpack, hhist, flags, out);
  }
}

// Round 8
// 10563.583 us; speedup vs baseline: 1.0686x; 1.0089x over previous
//
#include <hip/hip_runtime.h>
#include <hip/hip_bf16.h>
#include <stdint.h>

typedef unsigned int u32;
typedef unsigned short u16;
typedef short bf16x8 __attribute__((ext_vector_type(8)));
typedef float f32x4 __attribute__((ext_vector_type(4)));
typedef u32 u32x4 __attribute__((ext_vector_type(4)));

#define T_STEPS 1024
#define BATCH   64
#define DIM     1024
#define NWG     64      // one WG per 16 hidden columns
#define NTHR    512     // 8 waves
#define NMAT    3       // z, r, h
#define KSLICE  256     // K per wave (waves 0-3: x-part, 4-7: h-part)
#define DCOLS   16      // hidden columns per WG
#define HROW    512     // u32 per packed H row (1024 bf16 / 2)
#define SENT    0xFFFFFFFFu   // bf16 NaN|NaN — unreachable by real H (|H|<=1)

// round-to-nearest-even f32 -> bf16 bits
__device__ __forceinline__ u16 f2bf(float f) {
  u32 u = __float_as_uint(f);
  return (u16)((u + 0x7FFFu + ((u >> 16) & 1u)) >> 16);
}
__device__ __forceinline__ float sigm(float x) { return 1.0f / (1.0f + __expf(-x)); }
__device__ __forceinline__ float tanh_f(float x) {
  x = fminf(8.0f, fmaxf(-8.0f, x));
  float e = __expf(2.0f * x);
  return (e - 1.0f) / (e + 1.0f);
}

// ---------------- one-time input f32 -> bf16 conversion ----------------
__global__ void gru_xconv(const float* __restrict__ in, u32* __restrict__ xb) {
  size_t i = (size_t)(blockIdx.x * 256 + threadIdx.x) * 8;
  f32x4 lo = *(const f32x4*)(in + i);
  f32x4 hi = *(const f32x4*)(in + i + 4);
  u32x4 o;
  o[0] = ((u32)f2bf(lo[1]) << 16) | f2bf(lo[0]);
  o[1] = ((u32)f2bf(lo[3]) << 16) | f2bf(lo[2]);
  o[2] = ((u32)f2bf(hi[1]) << 16) | f2bf(hi[0]);
  o[3] = ((u32)f2bf(hi[3]) << 16) | f2bf(hi[2]);
  *(u32x4*)(xb + i / 2) = o;
}

// ---------------- pack weights into per-wave register-fragment order ----------------
// k = (wv&3)*256 + ks*32 + (lane>>4)*8 + j   (contiguous-8 kappa; A-loads use the SAME kappa)
// col = wg*16 + (lane&15)
__global__ void gru_pack(const float* __restrict__ Wxz, const float* __restrict__ Whz,
                         const float* __restrict__ Wxr, const float* __restrict__ Whr,
                         const float* __restrict__ Wxh, const float* __restrict__ Whh,
                         u16* __restrict__ wpack) {
  int idx = blockIdx.x * 256 + threadIdx.x;
  if (idx >= NWG * 8 * NMAT * 8 * 64) return;
  int lane = idx & 63; int rest = idx >> 6;
  int ks = rest & 7;  rest >>= 3;
  int n  = rest % NMAT; rest /= NMAT;
  int wv = rest & 7;  int wg = rest >> 3;
  int d  = wg * DCOLS + (lane & 15);
  int k0 = (wv & 3) * KSLICE + ks * 32 + (lane >> 4) * 8;
  const float* W = (wv < 4) ? ((n == 0) ? Wxz : (n == 1) ? Wxr : Wxh)
                            : ((n == 0) ? Whz : (n == 1) ? Whr : Whh);
  u16* dst = wpack + (size_t)idx * 8;
#pragma unroll
  for (int j = 0; j < 8; ++j)
    dst[j] = f2bf(W[(size_t)(k0 + j) * DIM + d]);
}

// coherent 16B load with literal byte offset (bypass L1/L2 -> read coherence point)
#define LOADX4C(dst, ptr, OFF) \
  asm volatile("global_load_dwordx4 %0, %1, off offset:" #OFF " sc0 sc1" \
               : "=v"(dst) : "v"(ptr))

#define HLOAD(B, pm) \
  LOADX4C(B##0, (pm), 0);   LOADX4C(B##1, (pm), 64);  LOADX4C(B##2, (pm), 128); \
  LOADX4C(B##3, (pm), 192); LOADX4C(B##4, (pm), 256); LOADX4C(B##5, (pm), 320); \
  LOADX4C(B##6, (pm), 384); LOADX4C(B##7, (pm), 448)

#define MF1(B, ks, m) { bf16x8 _a = __builtin_bit_cast(bf16x8, B); \
  acc[m][0] = __builtin_amdgcn_mfma_f32_16x16x32_bf16(_a, breg[0][ks], acc[m][0], 0, 0, 0); \
  acc[m][1] = __builtin_amdgcn_mfma_f32_16x16x32_bf16(_a, breg[1][ks], acc[m][1], 0, 0, 0); \
  acc[m][2] = __builtin_amdgcn_mfma_f32_16x16x32_bf16(_a, breg[2][ks], acc[m][2], 0, 0, 0); }

#define HMFMA(B, m) \
  MF1(B##0, 0, m); MF1(B##1, 1, m); MF1(B##2, 2, m); MF1(B##3, 3, m); \
  MF1(B##4, 4, m); MF1(B##5, 5, m); MF1(B##6, 6, m); MF1(B##7, 7, m)

#define WAITV(N) \
  asm volatile("s_waitcnt vmcnt(" #N ")" ::: "memory"); \
  __builtin_amdgcn_sched_barrier(0)

// sentinel verify: every u32 of the group must differ from SENT (each word is a
// different producer-thread's store; word-level visibility is independent)
#define VER1(Bq) { bad |= (u32)(Bq[0] == SENT); bad |= (u32)(Bq[1] == SENT); \
                   bad |= (u32)(Bq[2] == SENT); bad |= (u32)(Bq[3] == SENT); }
#define VER8(B) VER1(B##0) VER1(B##1) VER1(B##2) VER1(B##3) \
                VER1(B##4) VER1(B##5) VER1(B##6) VER1(B##7)

// ---------------- persistent scan kernel ----------------
// DATA-AS-FLAG rendezvous: hhist slots are pre-sentineled (0xFFFFFFFF). Producers
// fire sc0 sc1 H stores and move on (no drain, no flag, no barrier-tail). Consumers
// poll one canary word per producer at the DATA, then load+verify+retry. Hop depth
// per step: 1 store-visibility transit + 1 sampling RT (was 4 transits with flags).
template <bool XB>
__launch_bounds__(NTHR, 2)
__global__ void gru_scan(const float* __restrict__ inputs, const u32* __restrict__ xbf,
                         const float* __restrict__ bz, const float* __restrict__ br,
                         const float* __restrict__ bh,
                         const u16* __restrict__ wpack,
                         u32* hhist, float* __restrict__ out) {
  // partials: 24B cell/lane (4 data words + 2 pad); <=2-way bank aliased (free). 144KB.
  __shared__ float part[8][4][NMAT][64][6];

  const int tid  = threadIdx.x;
  const int wg   = blockIdx.x;
  const int wv   = tid >> 6;
  const int lane = tid & 63;
  const int isH  = (wv >= 4);
  const int arow = lane & 15;
  const int akoff = (lane >> 4) * 8;

  // persistent B fragments: 24 x bf16x8; asm-laundered against remat/spill
  bf16x8 breg[NMAT][8];
  {
    const u16* wp = wpack + ((size_t)(wg * 8 + wv) * NMAT * 8 * 64) * 8;
#pragma unroll
    for (int n = 0; n < NMAT; ++n)
#pragma unroll
      for (int ks = 0; ks < 8; ++ks) {
        breg[n][ks] = *(const bf16x8*)(wp + ((n * 8 + ks) * 64 + lane) * 8);
        asm volatile("" : "+v"(breg[n][ks]));
      }
  }

  // elementwise ownership: thread -> (batch row, 2 adjacent d-columns)
  const int erow = tid >> 3;
  const int ep   = tid & 7;
  const int dbase = wg * DCOLS;
  const int d0 = dbase + 2 * ep;
  const float bz0 = bz[d0], bz1 = bz[d0 + 1];
  const float br0 = br[d0], br1 = br[d0 + 1];
  const float bh0 = bh[d0], bh1 = bh[d0 + 1];
  const int em = erow >> 4, er = erow & 15;
  const int cell0 = (er >> 2) * 16 + 2 * ep;   // partials cell for (row er, col 2ep)
  const int rr_rd = er & 3;                    // word within cell
  float hp0 = 0.f, hp1 = 0.f;                  // H_prev kept in f32 registers

  // canary address component: producer id this lane watches (16 producers/wave)
  const int cprod = ((wv - 4) & 3) * 16 + (lane & 15);

#pragma unroll 1
  for (int t = 0; t < T_STEPS; ++t) {
    f32x4 acc[4][NMAT];
#pragma unroll
    for (int m = 0; m < 4; ++m)
#pragma unroll
      for (int n = 0; n < NMAT; ++n)
        acc[m][n] = (f32x4){0.f, 0.f, 0.f, 0.f};

    if (!isH) {
      // ---- warm-touch inputs[t+1] slice into this XCD's L2 ----
      u32 tch = 0;
      if (t + 1 < T_STEPS) {
        constexpr int LPR = XB ? 8 : 16;       // 64B lines per row-slice
        const char* nb = XB
          ? (const char*)((const u16*)xbf + (size_t)(t + 1) * (BATCH * DIM) + wv * KSLICE)
          : (const char*)(inputs + (size_t)(t + 1) * (BATCH * DIM) + wv * KSLICE);
        constexpr int ROWB = XB ? (DIM * 2) : (DIM * 4);
#pragma unroll
        for (int i = 0; i < LPR; ++i) {
          int L = i * 64 + lane;
          const u32* tp = (const u32*)(nb + (size_t)(L / LPR) * ROWB + (L % LPR) * 64);
          tch ^= *tp;
        }
      }
      // ---- x-part GEMM ----
      if (XB) {
        const u16* xp = (const u16*)xbf + (size_t)t * (BATCH * DIM) + wv * KSLICE + akoff;
#pragma unroll
        for (int m = 0; m < 4; ++m) {
          const u16* rp = xp + (size_t)(m * 16 + arow) * DIM;
#pragma unroll
          for (int ks = 0; ks < 8; ++ks) {
            bf16x8 av = *(const bf16x8*)(rp + ks * 32);
            MF1(__builtin_bit_cast(u32x4, av), ks, m);
          }
        }
      } else {
        const float* xp = inputs + (size_t)t * (BATCH * DIM) + wv * KSLICE + akoff;
#pragma unroll
        for (int m = 0; m < 4; ++m) {
          const float* rp = xp + (size_t)(m * 16 + arow) * DIM;
#pragma unroll
          for (int ks = 0; ks < 8; ++ks) {
            f32x4 lo = *(const f32x4*)(rp + ks * 32);
            f32x4 hi = *(const f32x4*)(rp + ks * 32 + 4);
            bf16x8 av;
            av[0] = (short)f2bf(lo[0]); av[1] = (short)f2bf(lo[1]);
            av[2] = (short)f2bf(lo[2]); av[3] = (short)f2bf(lo[3]);
            av[4] = (short)f2bf(hi[0]); av[5] = (short)f2bf(hi[1]);
            av[6] = (short)f2bf(hi[2]); av[7] = (short)f2bf(hi[3]);
            MF1(__builtin_bit_cast(u32x4, av), ks, m);
          }
        }
      }
      asm volatile("" :: "v"(tch));   // keep touches live (rule #17)
    } else if (t > 0) {
      const u32* hslot = hhist + (size_t)(t - 1) * (BATCH * HROW);
      // ---- canary poll directly on the H(t-1) data (lane<16; 1 word/producer) ----
      {
        const u32* cp = hslot + (size_t)63 * HROW + cprod * 8 + 7;  // producer's tid=511 word
        float spin = 1.0f;
        for (;;) {
          u32 c;
          asm volatile("global_load_dword %0, %1, off sc0 sc1\n\t"
                       "s_waitcnt vmcnt(0)" : "=v"(c) : "v"(cp));
          if (__all((lane < 16) ? (int)(c != SENT) : 1)) break;
#pragma unroll
          for (int s = 0; s < 24; ++s) spin = __builtin_fmaf(spin, 1.0000001f, 1e-9f);
          asm volatile("" : "+v"(spin));
        }
      }
      // ---- h-part GEMM: pipelined coherent loads + sentinel verify + rare retry ----
      const u32* hb = hslot + (size_t)arow * HROW + (wv & 3) * 128 + (lane >> 4) * 4;
      u32x4 hA0, hA1, hA2, hA3, hA4, hA5, hA6, hA7;
      u32x4 hB0, hB1, hB2, hB3, hB4, hB5, hB6, hB7;
      for (;;) {
        u32 bad = 0;
        HLOAD(hA, hb);               // m=0 rows
        HLOAD(hB, hb + 8192);        // m=1 rows (16 rows * 512 u32)
        WAITV(8);                    // m0 retired
        VER8(hA); HMFMA(hA, 0);
        HLOAD(hA, hb + 16384);       // m=2
        WAITV(8);                    // m1 retired
        VER8(hB); HMFMA(hB, 1);
        HLOAD(hB, hb + 24576);       // m=3
        WAITV(8);                    // m2 retired
        VER8(hA); HMFMA(hA, 2);
        WAITV(0);                    // m3 retired
        VER8(hB); HMFMA(hB, 3);
        if (__all((int)(bad == 0))) break;
        // canary raced ahead of sibling stores: re-zero and retry (rare)
#pragma unroll
        for (int m = 0; m < 4; ++m)
#pragma unroll
          for (int n = 0; n < NMAT; ++n)
            acc[m][n] = (f32x4){0.f, 0.f, 0.f, 0.f};
      }
    }
    // (t==0 h-waves: zero partials, H(-1)=0)

    // ---- publish partials to LDS: lane-cell layout, ds_write_b64 pairs ----
#pragma unroll
    for (int m = 0; m < 4; ++m)
#pragma unroll
      for (int n = 0; n < NMAT; ++n) {
        *(float2*)&part[wv][m][n][lane][0] = make_float2(acc[m][n][0], acc[m][n][1]);
        *(float2*)&part[wv][m][n][lane][2] = make_float2(acc[m][n][2], acc[m][n][3]);
      }
    __syncthreads();

    // ---- reduce + gates (all 512 threads; 2 outputs each) ----
    float zp = bz0, zq = bz1, rp = br0, rq = br1;
    float xh0 = bh0, xh1 = bh1, hh0 = 0.f, hh1 = 0.f;
#pragma unroll
    for (int w = 0; w < 8; ++w) {
      zp += part[w][em][0][cell0][rr_rd];
      zq += part[w][em][0][cell0 + 1][rr_rd];
      rp += part[w][em][1][cell0][rr_rd];
      rq += part[w][em][1][cell0 + 1][rr_rd];
      float h0 = part[w][em][2][cell0][rr_rd];
      float h1 = part[w][em][2][cell0 + 1][rr_rd];
      if (w < 4) { xh0 += h0; xh1 += h1; }   // x-part of candidate (NOT scaled by R)
      else       { hh0 += h0; hh1 += h1; }   // recurrent part (scaled by R)
    }
    float z0 = sigm(zp), z1 = sigm(zq);
    float r0 = sigm(rp), r1 = sigm(rq);
    float th0 = tanh_f(xh0 + r0 * hh0);
    float th1 = tanh_f(xh1 + r1 * hh1);
    float hn0 = z0 * hp0 + (1.f - z0) * th0;
    float hn1 = z1 * hp1 + (1.f - z1) * th1;
    hp0 = hn0; hp1 = hn1;

    // publish H(t): fire-and-forget coherent store — the data IS the flag
    {
      u32 pk = ((u32)f2bf(hn1) << 16) | (u32)f2bf(hn0);
      u32* hp = hhist + (size_t)t * (BATCH * HROW)
                      + (size_t)erow * HROW + (dbase >> 1) + ep;
      asm volatile("global_store_dword %0, %1, off sc0 sc1" :: "v"(hp), "v"(pk) : "memory");
    }
    __syncthreads();   // LDS WAR protection for next iteration's partials write

    // out stores (plain cached); overlap next step
    float* op = out + (size_t)t * (BATCH * DIM) + (size_t)erow * DIM + d0;
    *(float2*)op = make_float2(hn0, hn1);
    if (t == T_STEPS - 1) {
      float* fo = out + (size_t)T_STEPS * (BATCH * DIM) + (size_t)erow * DIM + d0;
      *(float2*)fo = make_float2(hn0, hn1);
    }
  }
}

extern "C" void kernel_launch(void* const* d_in, const int* in_sizes, int n_in,
                              void* d_out, int out_size, void* d_ws, size_t ws_size,
                              hipStream_t stream) {
  const float* inputs = (const float*)d_in[0];
  const float* Wxz = (const float*)d_in[1];
  const float* Whz = (const float*)d_in[2];
  const float* bz  = (const float*)d_in[3];
  const float* Wxr = (const float*)d_in[4];
  const float* Whr = (const float*)d_in[5];
  const float* br  = (const float*)d_in[6];
  const float* Wxh = (const float*)d_in[7];
  const float* Whh = (const float*)d_in[8];
  const float* bh  = (const float*)d_in[9];
  float* out = (float*)d_out;

  // ws layout: [0,8K) spare | [8K, +128MB) H history (sentinel-filled, no-reuse)
  //            | wpack 12.6MB | xbf 128MB (optional)
  char* ws = (char*)d_ws;
  u32* hhist = (u32*)(ws + 8192);
  size_t hhist_bytes = (size_t)T_STEPS * BATCH * HROW * 4;   // 128MB
  u16* wpack = (u16*)(ws + 8192 + hhist_bytes);
  size_t wpack_bytes = (size_t)NWG * 8 * NMAT * 8 * 64 * 8 * 2;
  size_t base_need = 8192 + hhist_bytes + wpack_bytes;
  size_t xbf_off = (base_need + 4095) & ~(size_t)4095;
  u32* xbf = (u32*)(ws + xbf_off);
  size_t xbf_bytes = (size_t)T_STEPS * BATCH * DIM * 2;
  bool use_xb = (ws_size >= xbf_off + xbf_bytes);
  if (ws_size < base_need) return;  // insufficient workspace: fail visibly

  // re-arm sentinels EVERY call (graph replays don't re-poison ws)
  hipMemsetAsync(hhist, 0xFF, hhist_bytes, stream);

  const int total = NWG * 8 * NMAT * 8 * 64;
  hipLaunchKernelGGL(gru_pack, dim3((total + 255) / 256), dim3(256), 0, stream,
                     Wxz, Whz, Wxr, Whr, Wxh, Whh, wpack);
  if (use_xb) {
    hipLaunchKernelGGL(gru_xconv, dim3(T_STEPS * BATCH * DIM / 8 / 256), dim3(256), 0, stream,
                       inputs, xbf);
    hipLaunchKernelGGL(gru_scan<true>, dim3(NWG), dim3(NTHR), 0, stream,
                       inputs, xbf, bz, br, bh, wpack, hhist, out);
  } else {
    hipLaunchKernelGGL(gru_scan<false>, dim3(NWG), dim3(NTHR), 0, stream,
                       inputs, xbf, bz, br, bh, wpack, hhist, out);
  }
}